// Round 3
// baseline (366.934 us; speedup 1.0000x reference)
//
#include <hip/hip_runtime.h>

// B=16, A=3, H=W=128, V=85 -> rows = 786432, row: [box(4), obj, 80 cls].
// Out0: (rows,7) = [box, obj, cls_id, conf] zeroed where conf <= 0.25.
// Out1: targets copy (identity: all-zero rows map to zero).
//
// Structure: per-wave double-buffered DMA streaming, NO barriers.
// Each 64-thread block (1 wave) owns CPB chunks of 64 rows (21,760 B each).
// It keeps >=1 chunk of DMA in flight at all times via s_waitcnt vmcnt(22)
// discipline -- the barrier-drain (vmcnt(0) at __syncthreads) of the previous
// version is gone, so HBM stays covered during the LDS scan phase.

#define VROW 85
#define NCLS 80
#define OUTW 7
#define RPC 64                       // rows per chunk == lanes per wave
#define CHUNK_FLOATS (RPC * VROW)    // 5440 floats = 21,760 B, 16B-aligned/chunk
#define CPB 8                        // chunks per block -> grid 1536 @ 786432 rows
#define CONF_THRESHOLD 0.25f

#define AS1 __attribute__((address_space(1)))
#define AS3 __attribute__((address_space(3)))
// compile-time memory barrier: pins DMA-issue / scan / store ordering so the
// hand-placed vmcnt counts below stay valid.
#define CBAR() asm volatile("" ::: "memory")

// 22 vmcnt-counted ops per chunk: 21 x width-16 DMA (1 KB each) + 1 x width-4
// DMA for the 64-dword tail (5440 = 21*256 + 64). No VGPR round trip at all.
__device__ __forceinline__ void issue_chunk(const float* __restrict__ pred,
                                            float* buf, long long chunk,
                                            int lane) {
    const float* src = pred + chunk * (long long)CHUNK_FLOATS;
    #pragma unroll
    for (int it = 0; it < 21; ++it) {
        __builtin_amdgcn_global_load_lds(
            (const AS1 void*)(src + it * 256 + lane * 4),   // per-lane gptr
            (AS3 void*)((AS3 float*)buf + it * 256),        // wave-uniform base
            16, 0, 0);
    }
    __builtin_amdgcn_global_load_lds(
        (const AS1 void*)(src + 21 * 256 + lane),
        (AS3 void*)((AS3 float*)buf + 21 * 256),
        4, 0, 0);
}

__global__ __launch_bounds__(RPC) void yolo_post(
    const float* __restrict__ pred, float* __restrict__ out, int nchunks,
    const float4* __restrict__ tsrc, float4* __restrict__ tdst, int tvec) {
    // 2 x 21,760 B = 43,520 B -> 3 blocks/CU; ~129 KB of DMA in flight per CU.
    __shared__ float lds[2 * CHUNK_FLOATS];
    const int lane = threadIdx.x;
    const long long c0 = (long long)blockIdx.x * CPB;
    if (c0 >= nchunks) return;
    const long long left = (long long)nchunks - c0;
    const int n = left < CPB ? (int)left : CPB;

    // Fold the tiny targets copy into block 0 (saves a serialized launch).
    // Its loads are OLDER than every chunk DMA, so any vmcnt wait below also
    // covers them -- no accounting impact.
    if (blockIdx.x == 0) {
        for (int i = lane; i < tvec; i += RPC) tdst[i] = tsrc[i];
    }
    CBAR();
    issue_chunk(pred, lds, c0, lane);                       // chunk 0 -> buf 0
    if (n > 1) issue_chunk(pred, lds + CHUNK_FLOATS, c0 + 1, lane);  // -> buf 1
    CBAR();

    for (int i = 0; i < n; ++i) {
        // Ensure chunk i has landed. Everything issued after chunk i's 22 DMAs
        // is >= 22 ops (chunk i+1's DMAs), so vmcnt(22) is safe for non-last
        // iterations whether or not stores count in vmcnt; last iter drains.
        if (i < n - 1) asm volatile("s_waitcnt vmcnt(22)" ::: "memory");
        else           asm volatile("s_waitcnt vmcnt(0)"  ::: "memory");

        // Scan own row from wave-private LDS. Stride 85 (odd) -> 2-way bank
        // aliasing only, which is free on gfx950.
        const float* row = lds + (i & 1) * CHUNK_FLOATS + lane * VROW;
        const float b0 = row[0], b1 = row[1], b2 = row[2], b3 = row[3];
        const float obj = row[4];
        float best = row[5];
        int besti = 0;
        #pragma unroll
        for (int c = 1; c < NCLS; ++c) {
            const float v = row[5 + c];
            if (v > best) { best = v; besti = c; }  // strict > == jnp.argmax
        }
        const float conf = best * obj;
        const bool keep = conf > CONF_THRESHOLD;
        float* dst = out + ((c0 + i) * RPC + lane) * (long long)OUTW;
        dst[0] = keep ? b0 : 0.0f;
        dst[1] = keep ? b1 : 0.0f;
        dst[2] = keep ? b2 : 0.0f;
        dst[3] = keep ? b3 : 0.0f;
        dst[4] = keep ? obj : 0.0f;
        dst[5] = keep ? (float)besti : 0.0f;
        dst[6] = keep ? conf : 0.0f;

        CBAR();  // all reads of buf (i&1) are emitted before we overwrite it
        if (i + 2 < n)
            issue_chunk(pred, lds + (i & 1) * CHUNK_FLOATS, c0 + i + 2, lane);
        CBAR();
    }
}

// Generic tail for total_rows % 64 != 0 (not hit at the fixed problem size).
__global__ void yolo_tail(const float* __restrict__ pred,
                          float* __restrict__ out, long long row0, int nrows) {
    const int r = blockIdx.x * blockDim.x + threadIdx.x;
    if (r >= nrows) return;
    const float* p = pred + (row0 + r) * (long long)VROW;
    const float b0 = p[0], b1 = p[1], b2 = p[2], b3 = p[3], obj = p[4];
    float best = p[5];
    int besti = 0;
    for (int c = 1; c < NCLS; ++c) {
        const float v = p[5 + c];
        if (v > best) { best = v; besti = c; }
    }
    const float conf = best * obj;
    const bool keep = conf > CONF_THRESHOLD;
    float* dst = out + (row0 + r) * (long long)OUTW;
    dst[0] = keep ? b0 : 0.0f;
    dst[1] = keep ? b1 : 0.0f;
    dst[2] = keep ? b2 : 0.0f;
    dst[3] = keep ? b3 : 0.0f;
    dst[4] = keep ? obj : 0.0f;
    dst[5] = keep ? (float)besti : 0.0f;
    dst[6] = keep ? conf : 0.0f;
}

extern "C" void kernel_launch(void* const* d_in, const int* in_sizes, int n_in,
                              void* d_out, int out_size, void* d_ws, size_t ws_size,
                              hipStream_t stream) {
    const float* output  = (const float*)d_in[0];   // (16,3,128,128,85)
    // d_in[1] = anchors -- unused by the reference.
    const float* targets = (const float*)d_in[2];   // (16,50,5) = 4000 floats

    float* out = (float*)d_out;
    const int total_rows = in_sizes[0] / VROW;          // 786432
    const long long pred_out_elems = (long long)total_rows * OUTW;

    const int nchunks = total_rows / RPC;               // 12288
    const int rem = total_rows - nchunks * RPC;         // 0 at this size
    const int tvec = in_sizes[2] / 4;                   // 1000 float4s

    const int nblocks = (nchunks + CPB - 1) / CPB;      // 1536
    yolo_post<<<nblocks, RPC, 0, stream>>>(
        output, out, nchunks,
        (const float4*)targets, (float4*)(out + pred_out_elems), tvec);

    if (rem > 0)
        yolo_tail<<<(rem + 63) / 64, 64, 0, stream>>>(
            output, out, (long long)nchunks * RPC, rem);
}